// Round 4
// baseline (111.419 us; speedup 1.0000x reference)
//
#include <hip/hip_runtime.h>
#include <cstddef>

// ExpFilter via linearity: out = scan_t(X @ W^T + b) = scan_t(X) @ W^T + b*c(t)
//   c(t) = (1 - d^(t+1)) / (1 - d),  d = exp(-1)
// K0: split W -> bf16 hi/lo (plain [O][I]).
// K1: k_filter: Xf = scan_t(X) -> bf16 hi/lo, plain [m][k] (m = t*32+b).
//     chunk=128, warmup=32 (truncation <= d^33 ~ 5e-15).
// K2: k_gemm3: m97-style LDS-staged MFMA GEMM, 128x128 tile, BK=32,
//     global_load_lds width-16 staging, kq-plane LDS layout (conflict-free),
//     3-term split-bf16 (hi*hi + lo*hi + hi*lo).

#define DECAY  0.36787944117144233f
#define INV1MD 1.5819767068693265f   // 1/(1-d)

typedef __attribute__((ext_vector_type(8))) short short8;
typedef __attribute__((ext_vector_type(4))) float f32x4;

static constexpr int T_DIM = 2048, B_DIM = 32, K_DIM = 256, N_DIM = 256;
static constexpr int M_DIM = T_DIM * B_DIM;      // 65536
static constexpr int FCH = 128, FWARM = 32;      // filter chunking

__device__ __forceinline__ float bfbits2f(unsigned short u) {
  unsigned int x = ((unsigned int)u) << 16;
  return __builtin_bit_cast(float, x);
}
__device__ __forceinline__ short f2bf_s(float f) {
  __bf16 h = (__bf16)f;
  return __builtin_bit_cast(short, h);
}
__device__ __forceinline__ void gl_lds16(const void* g, void* l) {
  __builtin_amdgcn_global_load_lds(
      (const __attribute__((address_space(1))) unsigned int*)g,
      (__attribute__((address_space(3))) unsigned int*)l, 16, 0, 0);
}

// ---------------- K0: W (fp32 [O][I]) -> W_hi, W_lo bf16 ----------------
__global__ void k_split_w(const float* __restrict__ W, short* __restrict__ Wh,
                          short* __restrict__ Wl) {
  int i = blockIdx.x * 256 + threadIdx.x;
  float w = W[i];
  short h = f2bf_s(w);
  Wh[i] = h;
  Wl[i] = f2bf_s(w - bfbits2f((unsigned short)h));
}

// ---------------- K1: Xf = scan_t(X) -> bf16 hi/lo, plain [m][256] ----------------
// grid (T/FCH=16, B=32) x 256 thr; thread owns channel (b = blockIdx.y, i = tid).
__global__ __launch_bounds__(256)
void k_filter(const float* __restrict__ X, short* __restrict__ Xfh,
              short* __restrict__ Xfl) {
  const int i  = threadIdx.x;
  const int b  = blockIdx.y;
  const int c  = blockIdx.x;
  const int t0 = c * FCH;
  const int ts = c ? (t0 - FWARM) : 0;
  const float d = DECAY;

  const float* p = X + (size_t)ts * 8192 + b * 256 + i;
  float s = 0.f;
  #pragma unroll 4
  for (int t = ts; t < t0; ++t) { s = fmaf(d, s, *p); p += 8192; }

  size_t o = (size_t)t0 * 8192 + b * 256 + i;
  #pragma unroll 4
  for (int t = 0; t < FCH; ++t) {
    s = fmaf(d, s, *p); p += 8192;
    short h = f2bf_s(s);
    Xfh[o] = h;
    Xfl[o] = f2bf_s(s - bfbits2f((unsigned short)h));
    o += 8192;
  }
}

// ---------------- K2: out = Xf @ W^T + b*c(t), m97-style ----------------
// grid (M/128=512, N/128=2) x 256 thr = 4 waves (2x2). BK=32, 8 K-steps.
// LDS: 4 tiles x 8 KiB: [kq(4)][row(128)][16B]. Wave w stages buffer w.
__global__ __launch_bounds__(256, 4)
void k_gemm3(const short* __restrict__ Xfh, const short* __restrict__ Xfl,
             const short* __restrict__ Wh, const short* __restrict__ Wl,
             const float* __restrict__ bias, float* __restrict__ out) {
  __shared__ __align__(16) char lds[32768];

  const int tid   = threadIdx.x;
  const int lane  = tid & 63;
  const int wv    = tid >> 6;
  const int row16 = lane & 15;
  const int kq    = lane >> 4;
  const int rg    = wv >> 1;           // row half (x64)
  const int cg    = wv & 1;            // col half (x64)
  const int m0    = blockIdx.x * 128;
  const int n0    = blockIdx.y * 128;

  // wave w stages buffer w: 0=A_hi 1=A_lo 2=B_hi 3=B_lo
  const short* sbase = (wv == 0) ? Xfh + (size_t)m0 * 256
                     : (wv == 1) ? Xfl + (size_t)m0 * 256
                     : (wv == 2) ? Wh + (size_t)n0 * 256
                                 : Wl + (size_t)n0 * 256;
  char* const lbase = lds + wv * 8192;

  // stage K-slice kt: 8 issues; issue jj covers rows (jj&1)*64+lane, kq=jj>>1.
  // LDS slot (row, kq) <- global (sbase + row*256 + kt*32 + kq*8), 16 B.
  auto stage = [&](int kt) {
    #pragma unroll
    for (int jj = 0; jj < 8; ++jj) {
      const short* src =
          sbase + (size_t)((jj & 1) * 64 + lane) * 256 + kt * 32 + (jj >> 1) * 8;
      gl_lds16(src, lbase + jj * 1024);
    }
  };

  f32x4 acc[4][4] = {};
  stage(0);

  const int abyte = kq * 2048 + (rg * 64 + row16) * 16;
  const int bbyte = kq * 2048 + (cg * 64 + row16) * 16;

  for (int kt = 0;;) {
    __syncthreads();                   // staging visible (vmcnt drained)

    short8 ah[4], al[4];
    #pragma unroll
    for (int rt = 0; rt < 4; ++rt) {
      ah[rt] = *reinterpret_cast<const short8*>(lds + abyte + rt * 256);
      al[rt] = *reinterpret_cast<const short8*>(lds + 8192 + abyte + rt * 256);
    }
    #pragma unroll
    for (int ct = 0; ct < 4; ++ct) {
      short8 bh = *reinterpret_cast<const short8*>(lds + 16384 + bbyte + ct * 256);
      short8 bl = *reinterpret_cast<const short8*>(lds + 24576 + bbyte + ct * 256);
      #pragma unroll
      for (int rt = 0; rt < 4; ++rt) {
        acc[rt][ct] = __builtin_amdgcn_mfma_f32_16x16x32_bf16(ah[rt], bh, acc[rt][ct], 0, 0, 0);
        acc[rt][ct] = __builtin_amdgcn_mfma_f32_16x16x32_bf16(al[rt], bh, acc[rt][ct], 0, 0, 0);
        acc[rt][ct] = __builtin_amdgcn_mfma_f32_16x16x32_bf16(ah[rt], bl, acc[rt][ct], 0, 0, 0);
      }
    }

    __syncthreads();                   // all reads done; buffers free
    if (++kt == 8) break;
    stage(kt);
  }

  // epilogue: C/D layout col=lane&15, row=kq*4+j [validated R1-R3]
  #pragma unroll
  for (int ct = 0; ct < 4; ++ct) {
    const int col = n0 + cg * 64 + ct * 16 + row16;
    const float bv = bias[col];
    #pragma unroll
    for (int rt = 0; rt < 4; ++rt) {
      const int mb = m0 + rg * 64 + rt * 16 + kq * 4;
      #pragma unroll
      for (int j = 0; j < 4; ++j) {
        const int m = mb + j;
        const int t = m >> 5;
        const float cfac = (1.f - __expf(-(float)(t + 1))) * INV1MD;
        out[(size_t)m * 256 + col] = acc[rt][ct][j] + bv * cfac;
      }
    }
  }
}

// ---------------- fallback (ws too small): naive fp32 ----------------
__global__ void k_fb_gemm(const float* __restrict__ X, const float* __restrict__ W,
                          const float* __restrict__ bias, float* __restrict__ Y) {
  size_t idx = (size_t)blockIdx.x * 256 + threadIdx.x;
  int o = (int)(idx & 255);
  size_t m = idx >> 8;
  const float* x = X + m * 256;
  const float* w = W + (size_t)o * 256;
  float s = bias[o];
  for (int k = 0; k < 256; ++k) s = fmaf(x[k], w[k], s);
  Y[idx] = s;
}
__global__ void k_fb_scan(float* __restrict__ Y) {
  int ch = blockIdx.x * 256 + threadIdx.x;
  float s = 0.f;
  float* p = Y + ch;
  for (int t = 0; t < 2048; ++t) { s = fmaf(DECAY, s, *p); *p = s; p += 8192; }
}

extern "C" void kernel_launch(void* const* d_in, const int* in_sizes, int n_in,
                              void* d_out, int out_size, void* d_ws, size_t ws_size,
                              hipStream_t stream) {
  const float* X    = (const float*)d_in[0];
  const float* W    = (const float*)d_in[1];
  const float* bias = (const float*)d_in[2];
  float* out = (float*)d_out;

  const size_t w_elems  = (size_t)N_DIM * K_DIM;           // 65536
  const size_t xf_elems = (size_t)M_DIM * K_DIM;           // 16.7M
  const size_t need = (2 * w_elems + 2 * xf_elems) * sizeof(short);  // ~64.25 MiB

  if (ws_size >= need) {
    short* Wh  = (short*)d_ws;
    short* Wl  = Wh + w_elems;
    short* Xfh = Wl + w_elems;
    short* Xfl = Xfh + xf_elems;
    k_split_w<<<w_elems / 256, 256, 0, stream>>>(W, Wh, Wl);
    k_filter<<<dim3(T_DIM / FCH, B_DIM), 256, 0, stream>>>(X, Xfh, Xfl);
    k_gemm3<<<dim3(M_DIM / 128, N_DIM / 128), 256, 0, stream>>>(Xfh, Xfl, Wh, Wl,
                                                                bias, out);
  } else {
    k_fb_gemm<<<M_DIM, 256, 0, stream>>>(X, W, bias, out);
    k_fb_scan<<<32, 256, 0, stream>>>(out);
  }
}

// Round 5
// 74.417 us; speedup vs baseline: 1.4972x; 1.4972x over previous
//
#include <hip/hip_runtime.h>
#include <cstddef>

// ExpFilter via linearity: out = scan_t(X @ W^T + b) = scan_t(X) @ W^T + b*c(t)
//   c(t) = (1 - d^(t+1)) / (1 - d),  d = exp(-1)
// Intermediates stored PRE-TILED to make GEMM staging fully coalesced:
//   per 128-row panel: [kt(8)][kq(4)][row(128)][8 shorts]  (PS=32768 shorts)
//   row-space is B-major: m = b*2048 + t  (panel = b*16 + t/128)
// K0: k_split_w: W -> bf16 hi/lo, tiled.
// K1: k_filter: Xf = scan_t(X) -> bf16 hi/lo, tiled (LDS-staged subtiles,
//     coalesced 16B-chunk writes). chunk=64, warmup=32 (trunc <= d^33 ~ 5e-15).
// K2: k_gemm4: m97-style 2-barrier MFMA GEMM, 128x128 tile, BK=32; staging is
//     a LINEAR 8KB copy per buffer (global_load_lds 16B, lanes contiguous).

#define DECAY  0.36787944117144233f
#define INV1MD 1.5819767068693265f   // 1/(1-d)

typedef __attribute__((ext_vector_type(8))) short short8;
typedef __attribute__((ext_vector_type(4))) float f32x4;

static constexpr int T_DIM = 2048, B_DIM = 32, K_DIM = 256, N_DIM = 256;
static constexpr int M_DIM = T_DIM * B_DIM;   // 65536
static constexpr int FCH = 64, FWARM = 32, ST = 32;
static constexpr int PS  = 32768;             // shorts per 128-row panel
static constexpr int LYS = 260;               // fp32 stride of filter LDS tile

__device__ __forceinline__ float bfbits2f(unsigned short u) {
  unsigned int x = ((unsigned int)u) << 16;
  return __builtin_bit_cast(float, x);
}
__device__ __forceinline__ short f2bf_s(float f) {
  __bf16 h = (__bf16)f;
  return __builtin_bit_cast(short, h);
}
__device__ __forceinline__ void gl_lds16(const void* g, void* l) {
  __builtin_amdgcn_global_load_lds(
      (const __attribute__((address_space(1))) unsigned int*)g,
      (__attribute__((address_space(3))) unsigned int*)l, 16, 0, 0);
}

// ---------------- K0: W [O][I] fp32 -> tiled bf16 hi/lo ----------------
__global__ void k_split_w(const float* __restrict__ W, short* __restrict__ Wh,
                          short* __restrict__ Wl) {
  const int o = blockIdx.x, i = threadIdx.x;
  float w = W[o * 256 + i];
  short h = f2bf_s(w);
  size_t off = (size_t)(o >> 7) * PS + (i >> 5) * 4096 + ((i >> 3) & 3) * 1024 +
               (o & 127) * 8 + (i & 7);
  Wh[off] = h;
  Wl[off] = f2bf_s(w - bfbits2f((unsigned short)h));
}

// ---------------- K1: Xf = scan_t(X) -> tiled bf16 hi/lo ----------------
// grid (T/FCH=32, B=32) x 256 thr. Block owns (b, 64 t's) = half a panel.
// Per 32-t subtile: serial scan -> LDS fp32 -> cooperative tiled write
// (256 consecutive 16B chunks per store instruction = 4KB bursts).
__global__ __launch_bounds__(256)
void k_filter(const float* __restrict__ X, short* __restrict__ Xfh,
              short* __restrict__ Xfl) {
  __shared__ __align__(16) float ly[ST * LYS];
  const int tid = threadIdx.x;
  const int b = blockIdx.y, c = blockIdx.x;
  const int t0 = c * FCH;
  const int panel = b * 16 + (c >> 1);
  const int row0  = (c & 1) * 64;
  const float d = DECAY;

  float s = 0.f;
  const float* p = X + (size_t)(c ? t0 - FWARM : t0) * 8192 + b * 256 + tid;
  if (c) {
    #pragma unroll 4
    for (int t = 0; t < FWARM; ++t) { s = fmaf(d, s, *p); p += 8192; }
  }

  for (int st = 0; st < FCH / ST; ++st) {
    #pragma unroll 4
    for (int tl = 0; tl < ST; ++tl) {
      s = fmaf(d, s, *p); p += 8192;
      ly[tl * LYS + tid] = s;
    }
    __syncthreads();
    #pragma unroll
    for (int j = 0; j < 4; ++j) {
      const int chunk = tid + j * 256;       // 0..1023 = (kt,kq,row_local)
      const int rl = chunk & 31;
      const int kq = (chunk >> 5) & 3;
      const int kt = chunk >> 7;
      const float* lp = ly + rl * LYS + kt * 32 + kq * 8;
      f32x4 f0 = *reinterpret_cast<const f32x4*>(lp);
      f32x4 f1 = *reinterpret_cast<const f32x4*>(lp + 4);
      short8 hv, lv;
      #pragma unroll
      for (int e = 0; e < 4; ++e) {
        short h0 = f2bf_s(f0[e]);
        hv[e] = h0; lv[e] = f2bf_s(f0[e] - bfbits2f((unsigned short)h0));
        short h1 = f2bf_s(f1[e]);
        hv[4 + e] = h1; lv[4 + e] = f2bf_s(f1[e] - bfbits2f((unsigned short)h1));
      }
      const size_t off = (size_t)panel * PS + kt * 4096 + kq * 1024 +
                         (size_t)(row0 + st * 32 + rl) * 8;
      *reinterpret_cast<short8*>(Xfh + off) = hv;
      *reinterpret_cast<short8*>(Xfl + off) = lv;
    }
    __syncthreads();
  }
}

// ---------------- K2: out = Xf @ W^T + b*c(t) ----------------
// grid (M/128=512, N/128=2) x 256 thr = 4 waves (2x2). BK=32, 8 K-steps.
// LDS: 4 buffers x 8KB: [kq][row][16B]. Wave w stages buffer w as a LINEAR
// copy of the pre-tiled 8KB global slice (fully coalesced).
__global__ __launch_bounds__(256, 4)
void k_gemm4(const short* __restrict__ Xfh, const short* __restrict__ Xfl,
             const short* __restrict__ Wh, const short* __restrict__ Wl,
             const float* __restrict__ bias, float* __restrict__ out) {
  __shared__ __align__(16) char lds[32768];

  const int tid   = threadIdx.x;
  const int lane  = tid & 63;
  const int wv    = tid >> 6;
  const int row16 = lane & 15;
  const int kq    = lane >> 4;
  const int rg    = wv >> 1;
  const int cg    = wv & 1;
  const int bx    = blockIdx.x;   // row panel
  const int by    = blockIdx.y;   // col panel

  const short* sbase = (wv == 0) ? Xfh + (size_t)bx * PS
                     : (wv == 1) ? Xfl + (size_t)bx * PS
                     : (wv == 2) ? Wh + (size_t)by * PS
                                 : Wl + (size_t)by * PS;
  char* const lbase = lds + wv * 8192;

  auto stage = [&](int kt) {
    #pragma unroll
    for (int jj = 0; jj < 8; ++jj)
      gl_lds16(sbase + kt * 4096 + jj * 512 + lane * 8, lbase + jj * 1024);
  };

  f32x4 acc[4][4] = {};
  stage(0);

  const int abyte = kq * 2048 + (rg * 64 + row16) * 16;
  const int bbyte = kq * 2048 + (cg * 64 + row16) * 16;

  for (int kt = 0;;) {
    __syncthreads();                 // staging visible (vmcnt drained)

    short8 ah[4], al[4];
    #pragma unroll
    for (int rt = 0; rt < 4; ++rt) {
      ah[rt] = *reinterpret_cast<const short8*>(lds + abyte + rt * 256);
      al[rt] = *reinterpret_cast<const short8*>(lds + 8192 + abyte + rt * 256);
    }
    #pragma unroll
    for (int ct = 0; ct < 4; ++ct) {
      short8 bh = *reinterpret_cast<const short8*>(lds + 16384 + bbyte + ct * 256);
      short8 bl = *reinterpret_cast<const short8*>(lds + 24576 + bbyte + ct * 256);
      #pragma unroll
      for (int rt = 0; rt < 4; ++rt) {
        acc[rt][ct] = __builtin_amdgcn_mfma_f32_16x16x32_bf16(ah[rt], bh, acc[rt][ct], 0, 0, 0);
        acc[rt][ct] = __builtin_amdgcn_mfma_f32_16x16x32_bf16(al[rt], bh, acc[rt][ct], 0, 0, 0);
        acc[rt][ct] = __builtin_amdgcn_mfma_f32_16x16x32_bf16(ah[rt], bl, acc[rt][ct], 0, 0, 0);
      }
    }

    __syncthreads();                 // all reads done; buffers free
    if (++kt == 8) break;
    stage(kt);
  }

  // epilogue: C/D col=lane&15, row=kq*4+j [validated]; m is B-major.
  #pragma unroll
  for (int ct = 0; ct < 4; ++ct) {
    const int col = by * 128 + cg * 64 + ct * 16 + row16;
    const float bv = bias[col];
    #pragma unroll
    for (int rt = 0; rt < 4; ++rt) {
      const int mb = bx * 128 + rg * 64 + rt * 16 + kq * 4;
      #pragma unroll
      for (int j = 0; j < 4; ++j) {
        const int m  = mb + j;
        const int t  = m & 2047;
        const int bb = m >> 11;
        const float cfac = (1.f - __expf(-(float)(t + 1))) * INV1MD;
        out[((size_t)t * 32 + bb) * 256 + col] = acc[rt][ct][j] + bv * cfac;
      }
    }
  }
}

// ---------------- fallback (ws too small): naive fp32 ----------------
__global__ void k_fb_gemm(const float* __restrict__ X, const float* __restrict__ W,
                          const float* __restrict__ bias, float* __restrict__ Y) {
  size_t idx = (size_t)blockIdx.x * 256 + threadIdx.x;
  int o = (int)(idx & 255);
  size_t m = idx >> 8;
  const float* x = X + m * 256;
  const float* w = W + (size_t)o * 256;
  float s = bias[o];
  for (int k = 0; k < 256; ++k) s = fmaf(x[k], w[k], s);
  Y[idx] = s;
}
__global__ void k_fb_scan(float* __restrict__ Y) {
  int ch = blockIdx.x * 256 + threadIdx.x;
  float s = 0.f;
  float* p = Y + ch;
  for (int t = 0; t < 2048; ++t) { s = fmaf(DECAY, s, *p); *p = s; p += 8192; }
}

extern "C" void kernel_launch(void* const* d_in, const int* in_sizes, int n_in,
                              void* d_out, int out_size, void* d_ws, size_t ws_size,
                              hipStream_t stream) {
  const float* X    = (const float*)d_in[0];
  const float* W    = (const float*)d_in[1];
  const float* bias = (const float*)d_in[2];
  float* out = (float*)d_out;

  const size_t w_elems  = (size_t)N_DIM * K_DIM;           // 65536
  const size_t xf_elems = (size_t)M_DIM * K_DIM;           // 16.7M
  const size_t need = (2 * w_elems + 2 * xf_elems) * sizeof(short);  // ~64.25 MiB

  if (ws_size >= need) {
    short* Wh  = (short*)d_ws;
    short* Wl  = Wh + w_elems;
    short* Xfh = Wl + w_elems;
    short* Xfl = Xfh + xf_elems;
    k_split_w<<<N_DIM, 256, 0, stream>>>(W, Wh, Wl);
    k_filter<<<dim3(T_DIM / FCH, B_DIM), 256, 0, stream>>>(X, Xfh, Xfl);
    k_gemm4<<<dim3(M_DIM / 128, N_DIM / 128), 256, 0, stream>>>(Xfh, Xfl, Wh, Wl,
                                                                bias, out);
  } else {
    k_fb_gemm<<<M_DIM, 256, 0, stream>>>(X, W, bias, out);
    k_fb_scan<<<32, 256, 0, stream>>>(out);
  }
}

// Round 6
// 53.408 us; speedup vs baseline: 2.0862x; 1.3934x over previous
//
#include <hip/hip_runtime.h>
#include <cstddef>

// ExpFilter fused via linearity: out = scan_t(X) @ W^T + b*c(t)
//   c(t) = (1 - d^(t+1)) / (1 - d),  d = exp(-1)
// K0: k_split_w: W -> bf16 hi/lo, pre-tiled panels [kt(8)][kq(4)][row(128)][8].
// K1: k_fused: block = (64 t-rows, one b). Phase A: 4 waves scan X k-channels
//     (wave owns 64 channels, lane owns 1; 32-step warmup, trunc <= d^33~5e-15),
//     writing bf16 hi/lo A-tile to XOR-swizzled LDS. One barrier. Phase B:
//     streaming MFMA GEMM (W frags from L2-resident tiled panels), 3-term
//     split-bf16, epilogue adds bias*cfac. No Xf intermediate in HBM.

#define DECAY  0.36787944117144233f
#define INV1MD 1.5819767068693265f   // 1/(1-d)

typedef __attribute__((ext_vector_type(8))) short short8;
typedef __attribute__((ext_vector_type(4))) float f32x4;

static constexpr int T_DIM = 2048, B_DIM = 32, K_DIM = 256, N_DIM = 256;
static constexpr int M_DIM = T_DIM * B_DIM;   // 65536
static constexpr int PS  = 32768;             // shorts per 128-row W panel
static constexpr int TCH = 64;                // t-rows per block

__device__ __forceinline__ float bfbits2f(unsigned short u) {
  unsigned int x = ((unsigned int)u) << 16;
  return __builtin_bit_cast(float, x);
}
__device__ __forceinline__ short f2bf_s(float f) {
  __bf16 h = (__bf16)f;
  return __builtin_bit_cast(short, h);
}

// ---------------- K0: W [O][I] fp32 -> tiled bf16 hi/lo ----------------
__global__ void k_split_w(const float* __restrict__ W, short* __restrict__ Wh,
                          short* __restrict__ Wl) {
  const int o = blockIdx.x, i = threadIdx.x;
  float w = W[o * 256 + i];
  short h = f2bf_s(w);
  size_t off = (size_t)(o >> 7) * PS + (i >> 5) * 4096 + ((i >> 3) & 3) * 1024 +
               (o & 127) * 8 + (i & 7);
  Wh[off] = h;
  Wl[off] = f2bf_s(w - bfbits2f((unsigned short)h));
}

// ---- Phase A helper: scan NB*16 rows (first (NB-4)*16 = warmup), store 64 ----
// Lane owns one k-channel. ldsA: hi plane @0, lo @32768; row stride 512 B,
// byte ^= (row&7)<<4 (write: 128B contiguous per wave -> clean).
template <int NB>
__device__ __forceinline__ void prep_scan(const float* __restrict__ Xp,
                                          char* __restrict__ ldsA, int kbyte) {
  constexpr int WARMB = NB - 4;
  float xb[2][16];
  #pragma unroll
  for (int j = 0; j < 16; ++j) xb[0][j] = Xp[(size_t)j * 8192];
  float s = 0.f;
  #pragma unroll
  for (int ib = 0; ib < NB; ++ib) {
    if (ib + 1 < NB) {                    // issue next batch (16 in flight)
      const float* q = Xp + (size_t)(ib + 1) * 16 * 8192;
      #pragma unroll
      for (int j = 0; j < 16; ++j) xb[(ib + 1) & 1][j] = q[(size_t)j * 8192];
    }
    #pragma unroll
    for (int j = 0; j < 16; ++j) {
      s = fmaf(DECAY, s, xb[ib & 1][j]);
      if (ib >= WARMB) {
        const int row = (ib - WARMB) * 16 + j;
        short h = f2bf_s(s);
        short l = f2bf_s(s - bfbits2f((unsigned short)h));
        const int byte = (row * 512 + kbyte) ^ ((row & 7) << 4);
        *reinterpret_cast<short*>(ldsA + byte)         = h;
        *reinterpret_cast<short*>(ldsA + 32768 + byte) = l;
      }
    }
  }
}

// ---------------- K1: fused scan + GEMM ----------------
// grid (T/64=32, B=32) x 256 thr = 4 waves (rg=wv>>1 rows, cg=wv&1 cols).
__global__ __launch_bounds__(256, 2)
void k_fused(const float* __restrict__ X, const short* __restrict__ Wth,
             const short* __restrict__ Wtl, const float* __restrict__ bias,
             float* __restrict__ out) {
  __shared__ __align__(16) char ldsA[65536];   // A hi @0, A lo @32768
  __shared__ float cfac[TCH];

  const int tid  = threadIdx.x;
  const int lane = tid & 63;
  const int wv   = tid >> 6;
  const int c    = blockIdx.x;
  const int b    = blockIdx.y;
  const int t0   = c * TCH;
  const int k    = wv * 64 + lane;             // this lane's scan channel

  if (tid < TCH)
    cfac[tid] = (1.f - __expf(-(float)(t0 + tid + 1))) * INV1MD;

  if (c == 0)
    prep_scan<4>(X + (size_t)t0 * 8192 + b * 256 + k, ldsA, k * 2);
  else
    prep_scan<6>(X + (size_t)(t0 - 32) * 8192 + b * 256 + k, ldsA, k * 2);
  __syncthreads();                             // A-tile + cfac ready

  const int row16 = lane & 15;
  const int kq    = lane >> 4;
  const int rg    = wv >> 1;
  const int cg    = wv & 1;
  const short* Whp = Wth + (size_t)cg * PS;    // this wave's 128-col W panel
  const short* Wlp = Wtl + (size_t)cg * PS;

  f32x4 acc[2][8] = {};
  #pragma unroll 2
  for (int kt = 0; kt < 8; ++kt) {
    short8 bh[8], bl[8], ah[2], al[2];
    #pragma unroll
    for (int ct = 0; ct < 8; ++ct) {
      const size_t woff = (size_t)kt * 4096 + kq * 1024 + (ct * 16 + row16) * 8;
      bh[ct] = *reinterpret_cast<const short8*>(Whp + woff);
      bl[ct] = *reinterpret_cast<const short8*>(Wlp + woff);
    }
    #pragma unroll
    for (int rt = 0; rt < 2; ++rt) {
      const int row = rg * 32 + rt * 16 + row16;
      const int byte = (row * 512 + kt * 64 + kq * 16) ^ ((row & 7) << 4);
      ah[rt] = *reinterpret_cast<const short8*>(ldsA + byte);
      al[rt] = *reinterpret_cast<const short8*>(ldsA + 32768 + byte);
    }
    #pragma unroll
    for (int rt = 0; rt < 2; ++rt)
      #pragma unroll
      for (int ct = 0; ct < 8; ++ct) {
        acc[rt][ct] = __builtin_amdgcn_mfma_f32_16x16x32_bf16(ah[rt], bh[ct], acc[rt][ct], 0, 0, 0);
        acc[rt][ct] = __builtin_amdgcn_mfma_f32_16x16x32_bf16(al[rt], bh[ct], acc[rt][ct], 0, 0, 0);
        acc[rt][ct] = __builtin_amdgcn_mfma_f32_16x16x32_bf16(ah[rt], bl[ct], acc[rt][ct], 0, 0, 0);
      }
  }

  // epilogue: C/D col=lane&15, row=kq*4+j [validated R1-R5]; out[(t*32+b)*256+o]
  #pragma unroll
  for (int ct = 0; ct < 8; ++ct) {
    const int col = cg * 128 + ct * 16 + row16;
    const float bv = bias[col];
    #pragma unroll
    for (int rt = 0; rt < 2; ++rt)
      #pragma unroll
      for (int j = 0; j < 4; ++j) {
        const int ml = rg * 32 + rt * 16 + kq * 4 + j;
        out[((size_t)(t0 + ml) * 32 + b) * 256 + col] =
            acc[rt][ct][j] + bv * cfac[ml];
      }
  }
}

// ---------------- fallback (ws too small): naive fp32 ----------------
__global__ void k_fb_gemm(const float* __restrict__ X, const float* __restrict__ W,
                          const float* __restrict__ bias, float* __restrict__ Y) {
  size_t idx = (size_t)blockIdx.x * 256 + threadIdx.x;
  int o = (int)(idx & 255);
  size_t m = idx >> 8;
  const float* x = X + m * 256;
  const float* w = W + (size_t)o * 256;
  float s = bias[o];
  for (int k = 0; k < 256; ++k) s = fmaf(x[k], w[k], s);
  Y[idx] = s;
}
__global__ void k_fb_scan(float* __restrict__ Y) {
  int ch = blockIdx.x * 256 + threadIdx.x;
  float s = 0.f;
  float* p = Y + ch;
  for (int t = 0; t < 2048; ++t) { s = fmaf(DECAY, s, *p); *p = s; p += 8192; }
}

extern "C" void kernel_launch(void* const* d_in, const int* in_sizes, int n_in,
                              void* d_out, int out_size, void* d_ws, size_t ws_size,
                              hipStream_t stream) {
  const float* X    = (const float*)d_in[0];
  const float* W    = (const float*)d_in[1];
  const float* bias = (const float*)d_in[2];
  float* out = (float*)d_out;

  const size_t w_elems = (size_t)N_DIM * K_DIM;                 // 65536
  const size_t need    = 2 * w_elems * sizeof(short);           // 256 KiB

  if (ws_size >= need) {
    short* Wh = (short*)d_ws;
    short* Wl = Wh + w_elems;
    k_split_w<<<N_DIM, 256, 0, stream>>>(W, Wh, Wl);
    k_fused<<<dim3(T_DIM / TCH, B_DIM), 256, 0, stream>>>(X, Wh, Wl, bias, out);
  } else {
    k_fb_gemm<<<M_DIM, 256, 0, stream>>>(X, W, bias, out);
    k_fb_scan<<<32, 256, 0, stream>>>(out);
  }
}